// Round 11
// baseline (1906.677 us; speedup 1.0000x reference)
//
#include <hip/hip_runtime.h>
#include <math.h>

#define H 1024
#define BATCH 512
#define KSTEPS 96
#define KH ((long)KSTEPS * H)

typedef __attribute__((ext_vector_type(8))) short short8;
typedef __attribute__((ext_vector_type(16))) float f32x16;

__device__ __forceinline__ unsigned short f2bf(float x) {
    union { float f; unsigned int u; } v; v.f = x;
    unsigned int r = v.u + 0x7fffu + ((v.u >> 16) & 1u);
    return (unsigned short)(r >> 16);
}
__device__ __forceinline__ float bf2f(unsigned short h) {
    union { unsigned int u; float f; } v; v.u = ((unsigned int)h) << 16;
    return v.f;
}

// async global->LDS 16B/lane; dst wave-uniform base (HW adds lane*16)
__device__ __forceinline__ void glds16(const void* g, void* l) {
    __builtin_amdgcn_global_load_lds(
        (const __attribute__((address_space(1))) void*)g,
        (__attribute__((address_space(3))) void*)l, 16, 0, 0);
}
#define MEMFENCE asm volatile("" ::: "memory")

// ---------------------------------------------------------------------------
// Workspace layouts (32x32x16 MFMA fragment order, same as r9/r10):
//  blob0/blob1: [32 tc][64 by][2 s][2 jt][2 kg][64 l][8 e] bf16
//  bcJ: [4096] f32 J-interleaved fused biases
//  hTa/hTb: [32 tc][4 bx][2 s][2 mh][2 mt][2 kg][64 l][8 e] bf16 hi/lo
//  bar: [512] u32 — [g*32] group counters (g=0..7), [256] global, [288] go-epoch
// ---------------------------------------------------------------------------

__global__ void prep_w(const float* __restrict__ wih,
                       const float* __restrict__ whh,
                       unsigned short* __restrict__ blob0,
                       unsigned short* __restrict__ blob1)
{
    const unsigned int f = blockIdx.x * 256 + threadIdx.x;  // 0..8388607
    const int e  = f & 7;
    const int l  = (f >> 3) & 63;
    const int kg = (f >> 9) & 1;
    const int jt = (f >> 10) & 1;
    const int s  = (f >> 11) & 1;
    const int by = (f >> 12) & 63;
    const int tc = (f >> 18) & 31;
    const int b  = blockIdx.y;      // blob select

    const int J = by * 64 + jt * 32 + (l & 31);
    const int g = J & 3;
    const long j = J >> 2;
    const long k = (long)tc * 32 + kg * 16 + (l >> 5) * 8 + e;

    float v = 0.f;
    if (b == 1) {
        if (g == 0)      v = wih[j*1024 + k]           + whh[j*1024 + k];
        else if (g == 1) v = wih[(1024+j)*1024 + k]    + whh[(1024+j)*1024 + k];
        else if (g == 2) v = wih[(2048+j)*1024 + k];
        else             v = whh[(2048+j)*1024 + k];
    } else {
        if (g == 0)      v = whh[j*1024 + k];
        else if (g == 1) v = whh[(1024+j)*1024 + k];
        else if (g == 2) v = 0.f;
        else             v = whh[(2048+j)*1024 + k];
    }
    const unsigned short hi = f2bf(v);
    unsigned short* blob = (b == 0) ? blob0 : blob1;
    blob[f] = (s == 0) ? hi : f2bf(v - bf2f(hi));
}

__global__ void prep_bcJ(const float* __restrict__ bih,
                         const float* __restrict__ bhh,
                         float* __restrict__ bcJ,
                         unsigned int* __restrict__ bar)
{
    const int J = blockIdx.x * 256 + threadIdx.x;   // 0..4095
    const int g = J & 3;
    const int j = J >> 2;
    float v;
    if (g == 0)      v = bih[j]        + bhh[j];
    else if (g == 1) v = bih[1024 + j] + bhh[1024 + j];
    else if (g == 2) v = bih[2048 + j];
    else             v = bhh[2048 + j];
    bcJ[J] = v;
    if (blockIdx.x == 0) {                 // zero barrier state (512 u32)
        bar[threadIdx.x]       = 0u;
        bar[256 + threadIdx.x] = 0u;
    }
}

// c [512][1024] fp32 -> hT fragment layout (hi/lo bf16)
__global__ void prep_h0(const float* __restrict__ cin,
                        unsigned short* __restrict__ hT)
{
    const unsigned int f = blockIdx.x * 256 + threadIdx.x;   // 0..1048575
    const int e  = f & 7;
    const int l  = (f >> 3) & 63;
    const int kg = (f >> 9) & 1;
    const int mt = (f >> 10) & 1;
    const int mh = (f >> 11) & 1;
    const int s  = (f >> 12) & 1;
    const int bx = (f >> 13) & 3;
    const int tc = (f >> 15) & 31;

    const long m = bx * 128 + mh * 64 + mt * 32 + (l & 31);
    const long k = (long)tc * 32 + kg * 16 + (l >> 5) * 8 + e;

    const float v = cin[m * 1024 + k];
    const unsigned short hi = f2bf(v);
    hT[f] = (s == 0) ? hi : f2bf(v - bf2f(hi));
}

// ---------------------------------------------------------------------------
// Persistent GRU: all 96 steps in ONE cooperative launch.
// Grid 256 (1/CU), 512 threads (8 waves). Per-step core = r10 pipeline.
// Cross-step sync: two-level monotonic counter barrier (relaxed device-scope
// atomics, no agent-acquire fence) + per-block `buffer_inv sc1` (invalidate
// stale hT in L2; W refetches from Infinity Cache). hT written with sc0 sc1
// write-through stores. h_prev carried in registers (hp[4]); out write-only nt.
// ---------------------------------------------------------------------------
__global__ __launch_bounds__(512) void gru_all(
    const unsigned short* __restrict__ blob0,
    const unsigned short* __restrict__ blob1,
    unsigned short* __restrict__ hTa,
    unsigned short* __restrict__ hTb,
    const float* __restrict__ cin,
    const float* __restrict__ bcJ,
    float* __restrict__ out,
    unsigned int* bar)
{
    __shared__ __attribute__((aligned(16))) char smem[131072]; // W: 4gk x 3 x 8KB; D reuse 128KB

    const int tid  = threadIdx.x;
    const int lane = tid & 63;
    const int wv   = tid >> 6;        // 0..7
    const int gk   = wv >> 1;         // K-quarter 0..3
    const int mh   = wv & 1;          // m-half within 128

    const int id   = blockIdx.x;
    const int grp  = id & 7;          // XCD-aligned group (mapping heuristic only)
    const int slot = id >> 3;
    const int by   = grp * 8 + (slot & 7);   // 0..63  (J tile)
    const int bx   = slot >> 3;              // 0..3   (m tile)
    const long m0  = (long)bx * 128;

    // biases (read once, kept in regs)
    const float bb0 = bcJ[by*64 + (lane & 31)];
    const float bb1 = bcJ[by*64 + 32 + (lane & 31)];

    // h_prev carried in registers: same (m,j) per thread every step
    float hp[4];
    #pragma unroll
    for (int it = 0; it < 4; ++it) {
        const int qi = it * 512 + tid;
        const int jl = qi & 15;
        const int m  = qi >> 4;
        hp[it] = cin[(m0 + m) * 1024 + (long)by * 16 + jl];
    }

    #pragma unroll 1
    for (int k = 0; k < KSTEPS; ++k) {
        if (k > 0) {
            // ---- device barrier: wait for step k-1 complete everywhere ----
            __syncthreads();           // all waves: epilogue stores drained (vmcnt(0) at tail)
            if (tid == 0) {
                unsigned v = __hip_atomic_fetch_add(&bar[grp*32], 1u,
                                 __ATOMIC_RELAXED, __HIP_MEMORY_SCOPE_AGENT);
                if (v == 32u*(unsigned)k - 1u) {
                    unsigned w = __hip_atomic_fetch_add(&bar[256], 1u,
                                     __ATOMIC_RELAXED, __HIP_MEMORY_SCOPE_AGENT);
                    if (w == 8u*(unsigned)k - 1u)
                        __hip_atomic_store(&bar[288], (unsigned)k,
                                           __ATOMIC_RELAXED, __HIP_MEMORY_SCOPE_AGENT);
                }
                while (__hip_atomic_load(&bar[288], __ATOMIC_RELAXED,
                                         __HIP_MEMORY_SCOPE_AGENT) < (unsigned)k)
                    __builtin_amdgcn_s_sleep(2);
                asm volatile("buffer_inv sc1" ::: "memory");   // drop stale hT (and W) from L2
            }
            __syncthreads();
        }

        const unsigned short* wbl = (k == 0) ? blob0 : blob1;
        const unsigned short* hTr = (k & 1) ? hTb : hTa;
        unsigned short*       hTw = (k & 1) ? hTa : hTb;
        float* outk = out + (long)k * H;

        const char* wsrc = (const char*)wbl + (long)by * 8192;   // + tc*524288
        const char* hsrc = (const char*)hTr + (long)bx * 16384;  // + tc*65536

        f32x16 acc[2][2];   // [mt][jt]
        {
            const float a0 = (gk == 0) ? bb0 : 0.f;
            const float a1 = (gk == 0) ? bb1 : 0.f;
            #pragma unroll
            for (int mt = 0; mt < 2; ++mt)
                #pragma unroll
                for (int r = 0; r < 16; ++r) { acc[mt][0][r] = a0; acc[mt][1][r] = a1; }
        }

        short8 Aev[8], Aod[8];

        auto loadA = [&](int c, short8* A) {
            const char* hs = hsrc + (long)(gk * 8 + c) * 65536;
            #pragma unroll
            for (int s = 0; s < 2; ++s)
                #pragma unroll
                for (int mt = 0; mt < 2; ++mt)
                    #pragma unroll
                    for (int kg = 0; kg < 2; ++kg)
                        A[(s*2+mt)*2+kg] = *(const short8*)
                            (hs + (long)((((s*2+mh)*2+mt)*2)+kg)*1024 + lane*16);
        };
        auto stageW = [&](int c) {
            const char* ws = wsrc + (long)(gk * 8 + c) * 524288;
            char* dst = smem + gk * 24576 + (c % 3) * 8192;
            #pragma unroll
            for (int o = 0; o < 4; ++o)
                glds16(ws + (mh*4+o)*1024 + lane*16, dst + (mh*4+o)*1024);
        };
        auto compute = [&](const char* wb, const short8* A) {
            #pragma unroll
            for (int kg = 0; kg < 2; ++kg) {
                const short8 bh0 = *(const short8*)(wb + (0*4 + 0*2 + kg)*1024 + lane*16);
                const short8 bh1 = *(const short8*)(wb + (0*4 + 1*2 + kg)*1024 + lane*16);
                const short8 bl0 = *(const short8*)(wb + (1*4 + 0*2 + kg)*1024 + lane*16);
                const short8 bl1 = *(const short8*)(wb + (1*4 + 1*2 + kg)*1024 + lane*16);
                const short8 ah0 = A[0*4 + 0*2 + kg];
                const short8 ah1 = A[0*4 + 1*2 + kg];
                const short8 al0 = A[1*4 + 0*2 + kg];
                const short8 al1 = A[1*4 + 1*2 + kg];
                acc[0][0] = __builtin_amdgcn_mfma_f32_32x32x16_bf16(ah0, bh0, acc[0][0], 0, 0, 0);
                acc[0][1] = __builtin_amdgcn_mfma_f32_32x32x16_bf16(ah0, bh1, acc[0][1], 0, 0, 0);
                acc[1][0] = __builtin_amdgcn_mfma_f32_32x32x16_bf16(ah1, bh0, acc[1][0], 0, 0, 0);
                acc[1][1] = __builtin_amdgcn_mfma_f32_32x32x16_bf16(ah1, bh1, acc[1][1], 0, 0, 0);
                acc[0][0] = __builtin_amdgcn_mfma_f32_32x32x16_bf16(al0, bh0, acc[0][0], 0, 0, 0);
                acc[0][1] = __builtin_amdgcn_mfma_f32_32x32x16_bf16(al0, bh1, acc[0][1], 0, 0, 0);
                acc[1][0] = __builtin_amdgcn_mfma_f32_32x32x16_bf16(al1, bh0, acc[1][0], 0, 0, 0);
                acc[1][1] = __builtin_amdgcn_mfma_f32_32x32x16_bf16(al1, bh1, acc[1][1], 0, 0, 0);
                acc[0][0] = __builtin_amdgcn_mfma_f32_32x32x16_bf16(ah0, bl0, acc[0][0], 0, 0, 0);
                acc[0][1] = __builtin_amdgcn_mfma_f32_32x32x16_bf16(ah0, bl1, acc[0][1], 0, 0, 0);
                acc[1][0] = __builtin_amdgcn_mfma_f32_32x32x16_bf16(ah1, bl0, acc[1][0], 0, 0, 0);
                acc[1][1] = __builtin_amdgcn_mfma_f32_32x32x16_bf16(ah1, bl1, acc[1][1], 0, 0, 0);
            }
        };

        // ---- prologue: A(0), W(0), W(1) ----
        loadA(0, Aev); MEMFENCE;
        stageW(0); MEMFENCE;
        stageW(1); MEMFENCE;
        asm volatile("s_waitcnt vmcnt(4)" ::: "memory");   // A0,W0 landed; W1 flying
        __builtin_amdgcn_sched_barrier(0);
        __builtin_amdgcn_s_barrier();

        #define CHUNK(c, Acur, Anext)                                          \
        {                                                                      \
            if ((c) < 7) { loadA((c)+1, Anext); MEMFENCE; }                    \
            if ((c) < 6) { stageW((c)+2); MEMFENCE; }                          \
            __builtin_amdgcn_sched_barrier(0);                                 \
            __builtin_amdgcn_s_setprio(1);                                     \
            compute(smem + gk*24576 + ((c)%3)*8192, Acur);                     \
            __builtin_amdgcn_s_setprio(0);                                     \
            if ((c) <= 5)      asm volatile("s_waitcnt vmcnt(4)" ::: "memory");\
            else if ((c) == 6) asm volatile("s_waitcnt vmcnt(0)" ::: "memory");\
            __builtin_amdgcn_s_barrier();                                      \
        }
        CHUNK(0, Aev, Aod) CHUNK(1, Aod, Aev) CHUNK(2, Aev, Aod) CHUNK(3, Aod, Aev)
        CHUNK(4, Aev, Aod) CHUNK(5, Aod, Aev) CHUNK(6, Aev, Aod) CHUNK(7, Aod, Aev)
        #undef CHUNK

        __syncthreads();   // LDS reads done; smem becomes epilogue scratch

        // ---- epilogue: dump partials, 4-way reduce, gates ----
        float* D = (float*)smem;   // [4 gk][128 m][64 J]
        #pragma unroll
        for (int mt = 0; mt < 2; ++mt)
            #pragma unroll
            for (int jt = 0; jt < 2; ++jt)
                #pragma unroll
                for (int r = 0; r < 16; ++r) {
                    const int r32 = (r & 3) + 8 * (r >> 2) + 4 * (lane >> 5);
                    const int m  = mh * 64 + mt * 32 + r32;
                    const int J  = jt * 32 + (lane & 31);
                    D[(gk * 128 + m) * 64 + J] = acc[mt][jt][r];
                }
        __syncthreads();

        #pragma unroll
        for (int it = 0; it < 4; ++it) {
            const int qi = it * 512 + tid;     // 0..2047
            const int jl = qi & 15;
            const int m  = qi >> 4;            // 0..127
            const float4 s0 = *(const float4*)&D[(0*128 + m)*64 + 4*jl];
            const float4 s1 = *(const float4*)&D[(1*128 + m)*64 + 4*jl];
            const float4 s2 = *(const float4*)&D[(2*128 + m)*64 + 4*jl];
            const float4 s3 = *(const float4*)&D[(3*128 + m)*64 + 4*jl];
            const float gr = s0.x + s1.x + s2.x + s3.x;
            const float gz = s0.y + s1.y + s2.y + s3.y;
            const float gi = s0.z + s1.z + s2.z + s3.z;
            const float gh = s0.w + s1.w + s2.w + s3.w;

            const long mg = m0 + m;
            const long j  = (long)by * 16 + jl;

            const float rr = 1.f / (1.f + expf(-gr));
            const float zz = 1.f / (1.f + expf(-gz));
            const float nn = tanhf(fmaf(rr, gh, gi));
            const float o  = nn + zz * (hp[it] - nn);
            hp[it] = o;

            __builtin_nontemporal_store(o, &outk[mg * KH + j]);

            // hT writeback (next step's A fragment layout) — sc0 sc1 write-through
            const unsigned short hi = f2bf(o);
            const unsigned short lo = f2bf(o - bf2f(hi));
            const int kk  = (int)j;
            const int tc2 = kk >> 5;
            const int kg2 = (kk >> 4) & 1;
            const int lh  = (kk >> 3) & 1;
            const int e2  = kk & 7;
            const int mh2 = (m >> 6) & 1;
            const int mt2 = (m >> 5) & 1;
            const int row = m & 31;
            const long ub = ((((((long)tc2*4 + bx)*2 + 0)*2 + mh2)*2 + mt2)*2 + kg2)*512
                          + (lh*32 + row)*8 + e2;
            unsigned short* p0 = hTw + ub;
            unsigned short* p1 = hTw + ub + 4096;
            asm volatile("global_store_short %0, %1, off sc0 sc1"
                         :: "v"(p0), "v"((unsigned)hi) : "memory");
            asm volatile("global_store_short %0, %1, off sc0 sc1"
                         :: "v"(p1), "v"((unsigned)lo) : "memory");
        }
        asm volatile("s_waitcnt vmcnt(0)" ::: "memory");   // hT visible before barrier add
    }
}

// ---------------------------------------------------------------------------
extern "C" void kernel_launch(void* const* d_in, const int* in_sizes, int n_in,
                              void* d_out, int out_size, void* d_ws, size_t ws_size,
                              hipStream_t stream)
{
    const float* c   = (const float*)d_in[0];
    // d_in[1] = K (fixed 96)
    const float* wih = (const float*)d_in[2];
    const float* whh = (const float*)d_in[3];
    const float* bih = (const float*)d_in[4];
    const float* bhh = (const float*)d_in[5];
    float* out = (float*)d_out;

    unsigned short* blob0 = (unsigned short*)d_ws;            // 8.39M ushort
    unsigned short* blob1 = blob0 + 8388608L;
    float*          bcJ   = (float*)(blob1 + 8388608L);       // 4096 f32
    unsigned short* hTa   = (unsigned short*)(bcJ + 4096);    // 1M ushort
    unsigned short* hTb   = hTa + 1048576L;
    unsigned int*   bar   = (unsigned int*)(hTb + 1048576L);  // 512 u32

    prep_w  <<<dim3(32768, 2), 256, 0, stream>>>(wih, whh, blob0, blob1);
    prep_bcJ<<<dim3(16),       256, 0, stream>>>(bih, bhh, bcJ, bar);
    prep_h0 <<<dim3(4096),     256, 0, stream>>>(c, hTa);

    void* args[] = { (void*)&blob0, (void*)&blob1, (void*)&hTa, (void*)&hTb,
                     (void*)&c, (void*)&bcJ, (void*)&out, (void*)&bar };
    hipLaunchCooperativeKernel((const void*)gru_all, dim3(256), dim3(512),
                               args, 0, stream);
}

// Round 12
// 1500.281 us; speedup vs baseline: 1.2709x; 1.2709x over previous
//
#include <hip/hip_runtime.h>
#include <math.h>

#define H 1024
#define BATCH 512
#define KSTEPS 96
#define KH ((long)KSTEPS * H)

typedef __attribute__((ext_vector_type(8))) short short8;
typedef __attribute__((ext_vector_type(16))) float f32x16;

__device__ __forceinline__ unsigned short f2bf(float x) {
    union { float f; unsigned int u; } v; v.f = x;
    unsigned int r = v.u + 0x7fffu + ((v.u >> 16) & 1u);
    return (unsigned short)(r >> 16);
}
__device__ __forceinline__ float bf2f(unsigned short h) {
    union { unsigned int u; float f; } v; v.u = ((unsigned int)h) << 16;
    return v.f;
}

// async global->LDS 16B/lane; dst wave-uniform base (HW adds lane*16)
__device__ __forceinline__ void glds16(const void* g, void* l) {
    __builtin_amdgcn_global_load_lds(
        (const __attribute__((address_space(1))) void*)g,
        (__attribute__((address_space(3))) void*)l, 16, 0, 0);
}
#define MEMFENCE asm volatile("" ::: "memory")

// ---------------------------------------------------------------------------
// Workspace layouts (32x32x16 MFMA fragment order):
//  blob0/blob1: [32 tc][64 by][2 s][2 jt][2 kg][64 l][8 e] bf16   (W hi+lo)
//  bcJ: [4096] f32 J-interleaved fused biases
//  hTa/hTb: [32 tc][4 bx][2 s][2 mh][2 mt][2 kg][64 l][8 e] bf16 — ONLY s=0
//           (hi) is written/read now; s=1 half unused (2-product scheme).
//  bar: [512] u32 — [g*32] group counters, [256] global, [288] go-epoch
// ---------------------------------------------------------------------------

__global__ void prep_w(const float* __restrict__ wih,
                       const float* __restrict__ whh,
                       unsigned short* __restrict__ blob0,
                       unsigned short* __restrict__ blob1)
{
    const unsigned int f = blockIdx.x * 256 + threadIdx.x;  // 0..8388607
    const int e  = f & 7;
    const int l  = (f >> 3) & 63;
    const int kg = (f >> 9) & 1;
    const int jt = (f >> 10) & 1;
    const int s  = (f >> 11) & 1;
    const int by = (f >> 12) & 63;
    const int tc = (f >> 18) & 31;
    const int b  = blockIdx.y;      // blob select

    const int J = by * 64 + jt * 32 + (l & 31);
    const int g = J & 3;
    const long j = J >> 2;
    const long k = (long)tc * 32 + kg * 16 + (l >> 5) * 8 + e;

    float v = 0.f;
    if (b == 1) {
        if (g == 0)      v = wih[j*1024 + k]           + whh[j*1024 + k];
        else if (g == 1) v = wih[(1024+j)*1024 + k]    + whh[(1024+j)*1024 + k];
        else if (g == 2) v = wih[(2048+j)*1024 + k];
        else             v = whh[(2048+j)*1024 + k];
    } else {
        if (g == 0)      v = whh[j*1024 + k];
        else if (g == 1) v = whh[(1024+j)*1024 + k];
        else if (g == 2) v = 0.f;
        else             v = whh[(2048+j)*1024 + k];
    }
    const unsigned short hi = f2bf(v);
    unsigned short* blob = (b == 0) ? blob0 : blob1;
    blob[f] = (s == 0) ? hi : f2bf(v - bf2f(hi));
}

__global__ void prep_bcJ(const float* __restrict__ bih,
                         const float* __restrict__ bhh,
                         float* __restrict__ bcJ,
                         unsigned int* __restrict__ bar)
{
    const int J = blockIdx.x * 256 + threadIdx.x;   // 0..4095
    const int g = J & 3;
    const int j = J >> 2;
    float v;
    if (g == 0)      v = bih[j]        + bhh[j];
    else if (g == 1) v = bih[1024 + j] + bhh[1024 + j];
    else if (g == 2) v = bih[2048 + j];
    else             v = bhh[2048 + j];
    bcJ[J] = v;
    if (blockIdx.x == 0) {                 // zero barrier state (512 u32)
        bar[threadIdx.x]       = 0u;
        bar[256 + threadIdx.x] = 0u;
    }
}

// c [512][1024] fp32 -> hT fragment layout, hi (s=0) only
__global__ void prep_h0(const float* __restrict__ cin,
                        unsigned short* __restrict__ hT)
{
    const unsigned int f = blockIdx.x * 256 + threadIdx.x;   // 0..524287
    const int e  = f & 7;
    const int l  = (f >> 3) & 63;
    const int kg = (f >> 9) & 1;
    const int mt = (f >> 10) & 1;
    const int mh = (f >> 11) & 1;
    const int bx = (f >> 12) & 3;
    const int tc = (f >> 14) & 31;

    const long m = bx * 128 + mh * 64 + mt * 32 + (l & 31);
    const long k = (long)tc * 32 + kg * 16 + (l >> 5) * 8 + e;

    const long addr = (long)tc*32768 + bx*8192 /* s=0 */ + mh*2048 + mt*1024
                    + kg*512 + l*8 + e;
    hT[addr] = f2bf(cin[m * 1024 + k]);
}

// ---------------------------------------------------------------------------
// Persistent GRU: all 96 steps in ONE cooperative launch.
// Grid 256 (1/CU), 512 threads (8 waves). 2-PRODUCT split:
//   W·h ≈ (W_hi + W_lo)·h_hi  — W fp32-accurate, h bf16-rounded (error
//   non-accumulating: exact h carried in hp[] regs). 16 MFMA/chunk/wave.
// Cross-step sync: two-level counter barrier + per-block buffer_inv sc1.
// hT (hi only) written sc0 sc1 write-through; out write-only nontemporal.
// ---------------------------------------------------------------------------
__global__ __launch_bounds__(512) void gru_all(
    const unsigned short* __restrict__ blob0,
    const unsigned short* __restrict__ blob1,
    unsigned short* __restrict__ hTa,
    unsigned short* __restrict__ hTb,
    const float* __restrict__ cin,
    const float* __restrict__ bcJ,
    float* __restrict__ out,
    unsigned int* bar)
{
    __shared__ __attribute__((aligned(16))) char smem[131072]; // W: 4gk x 3 x 8KB; D reuse 128KB

    const int tid  = threadIdx.x;
    const int lane = tid & 63;
    const int wv   = tid >> 6;        // 0..7
    const int gk   = wv >> 1;         // K-quarter 0..3
    const int mh   = wv & 1;          // m-half within 128

    const int id   = blockIdx.x;
    const int grp  = id & 7;
    const int slot = id >> 3;
    const int by   = grp * 8 + (slot & 7);   // 0..63  (J tile)
    const int bx   = slot >> 3;              // 0..3   (m tile)
    const long m0  = (long)bx * 128;

    const float bb0 = bcJ[by*64 + (lane & 31)];
    const float bb1 = bcJ[by*64 + 32 + (lane & 31)];

    // h_prev carried in registers: same (m,j) per thread every step
    float hp[4];
    #pragma unroll
    for (int it = 0; it < 4; ++it) {
        const int qi = it * 512 + tid;
        const int jl = qi & 15;
        const int m  = qi >> 4;
        hp[it] = cin[(m0 + m) * 1024 + (long)by * 16 + jl];
    }

    #pragma unroll 1
    for (int k = 0; k < KSTEPS; ++k) {
        if (k > 0) {
            __syncthreads();           // epilogue stores drained (vmcnt(0) at tail)
            if (tid == 0) {
                unsigned v = __hip_atomic_fetch_add(&bar[grp*32], 1u,
                                 __ATOMIC_RELAXED, __HIP_MEMORY_SCOPE_AGENT);
                if (v == 32u*(unsigned)k - 1u) {
                    unsigned w = __hip_atomic_fetch_add(&bar[256], 1u,
                                     __ATOMIC_RELAXED, __HIP_MEMORY_SCOPE_AGENT);
                    if (w == 8u*(unsigned)k - 1u)
                        __hip_atomic_store(&bar[288], (unsigned)k,
                                           __ATOMIC_RELAXED, __HIP_MEMORY_SCOPE_AGENT);
                }
                while (__hip_atomic_load(&bar[288], __ATOMIC_RELAXED,
                                         __HIP_MEMORY_SCOPE_AGENT) < (unsigned)k)
                    __builtin_amdgcn_s_sleep(2);
                asm volatile("buffer_inv sc1" ::: "memory");   // drop stale hT from L2
            }
            __syncthreads();
        }

        const unsigned short* wbl = (k == 0) ? blob0 : blob1;
        const unsigned short* hTr = (k & 1) ? hTb : hTa;
        unsigned short*       hTw = (k & 1) ? hTa : hTb;
        float* outk = out + (long)k * H;

        const char* wsrc = (const char*)wbl + (long)by * 8192;   // + tc*524288
        const char* hsrc = (const char*)hTr + (long)bx * 16384;  // + tc*65536

        f32x16 acc[2][2];   // [mt][jt]
        {
            const float a0 = (gk == 0) ? bb0 : 0.f;
            const float a1 = (gk == 0) ? bb1 : 0.f;
            #pragma unroll
            for (int mt = 0; mt < 2; ++mt)
                #pragma unroll
                for (int r = 0; r < 16; ++r) { acc[mt][0][r] = a0; acc[mt][1][r] = a1; }
        }

        short8 Aev[4], Aod[4];   // [mt*2+kg], hi only

        auto loadA = [&](int c, short8* A) {
            const char* hs = hsrc + (long)(gk * 8 + c) * 65536;
            #pragma unroll
            for (int mt = 0; mt < 2; ++mt)
                #pragma unroll
                for (int kg = 0; kg < 2; ++kg)
                    A[mt*2+kg] = *(const short8*)
                        (hs + (long)(((mh*2+mt)*2)+kg)*1024 + lane*16);
        };
        auto stageW = [&](int c) {
            const char* ws = wsrc + (long)(gk * 8 + c) * 524288;
            char* dst = smem + gk * 24576 + (c % 3) * 8192;
            #pragma unroll
            for (int o = 0; o < 4; ++o)
                glds16(ws + (mh*4+o)*1024 + lane*16, dst + (mh*4+o)*1024);
        };
        auto compute = [&](const char* wb, const short8* A) {
            #pragma unroll
            for (int kg = 0; kg < 2; ++kg) {
                const short8 bh0 = *(const short8*)(wb + (0*4 + 0*2 + kg)*1024 + lane*16);
                const short8 bh1 = *(const short8*)(wb + (0*4 + 1*2 + kg)*1024 + lane*16);
                const short8 bl0 = *(const short8*)(wb + (1*4 + 0*2 + kg)*1024 + lane*16);
                const short8 bl1 = *(const short8*)(wb + (1*4 + 1*2 + kg)*1024 + lane*16);
                const short8 ah0 = A[0*2 + kg];
                const short8 ah1 = A[1*2 + kg];
                // p0: Ah*Bh (4 independent chains)
                acc[0][0] = __builtin_amdgcn_mfma_f32_32x32x16_bf16(ah0, bh0, acc[0][0], 0, 0, 0);
                acc[0][1] = __builtin_amdgcn_mfma_f32_32x32x16_bf16(ah0, bh1, acc[0][1], 0, 0, 0);
                acc[1][0] = __builtin_amdgcn_mfma_f32_32x32x16_bf16(ah1, bh0, acc[1][0], 0, 0, 0);
                acc[1][1] = __builtin_amdgcn_mfma_f32_32x32x16_bf16(ah1, bh1, acc[1][1], 0, 0, 0);
                // p1: Ah*Bl
                acc[0][0] = __builtin_amdgcn_mfma_f32_32x32x16_bf16(ah0, bl0, acc[0][0], 0, 0, 0);
                acc[0][1] = __builtin_amdgcn_mfma_f32_32x32x16_bf16(ah0, bl1, acc[0][1], 0, 0, 0);
                acc[1][0] = __builtin_amdgcn_mfma_f32_32x32x16_bf16(ah1, bl0, acc[1][0], 0, 0, 0);
                acc[1][1] = __builtin_amdgcn_mfma_f32_32x32x16_bf16(ah1, bl1, acc[1][1], 0, 0, 0);
            }
        };

        // ---- prologue: A(0), W(0), W(1) — 12 vmem ops; vmcnt(4) leaves W1 ----
        loadA(0, Aev); MEMFENCE;
        stageW(0); MEMFENCE;
        stageW(1); MEMFENCE;
        asm volatile("s_waitcnt vmcnt(4)" ::: "memory");
        __builtin_amdgcn_sched_barrier(0);
        __builtin_amdgcn_s_barrier();

        #define CHUNK(c, Acur, Anext)                                          \
        {                                                                      \
            if ((c) < 7) { loadA((c)+1, Anext); MEMFENCE; }                    \
            if ((c) < 6) { stageW((c)+2); MEMFENCE; }                          \
            __builtin_amdgcn_sched_barrier(0);                                 \
            __builtin_amdgcn_s_setprio(1);                                     \
            compute(smem + gk*24576 + ((c)%3)*8192, Acur);                     \
            __builtin_amdgcn_s_setprio(0);                                     \
            if ((c) <= 5)      asm volatile("s_waitcnt vmcnt(4)" ::: "memory");\
            else if ((c) == 6) asm volatile("s_waitcnt vmcnt(0)" ::: "memory");\
            __builtin_amdgcn_s_barrier();                                      \
        }
        CHUNK(0, Aev, Aod) CHUNK(1, Aod, Aev) CHUNK(2, Aev, Aod) CHUNK(3, Aod, Aev)
        CHUNK(4, Aev, Aod) CHUNK(5, Aod, Aev) CHUNK(6, Aev, Aod) CHUNK(7, Aod, Aev)
        #undef CHUNK

        __syncthreads();   // LDS reads done; smem becomes epilogue scratch

        // ---- epilogue: dump partials, 4-way reduce, gates ----
        float* D = (float*)smem;   // [4 gk][128 m][64 J]
        #pragma unroll
        for (int mt = 0; mt < 2; ++mt)
            #pragma unroll
            for (int jt = 0; jt < 2; ++jt)
                #pragma unroll
                for (int r = 0; r < 16; ++r) {
                    const int r32 = (r & 3) + 8 * (r >> 2) + 4 * (lane >> 5);
                    const int m  = mh * 64 + mt * 32 + r32;
                    const int J  = jt * 32 + (lane & 31);
                    D[(gk * 128 + m) * 64 + J] = acc[mt][jt][r];
                }
        __syncthreads();

        #pragma unroll
        for (int it = 0; it < 4; ++it) {
            const int qi = it * 512 + tid;     // 0..2047
            const int jl = qi & 15;
            const int m  = qi >> 4;            // 0..127
            const float4 s0 = *(const float4*)&D[(0*128 + m)*64 + 4*jl];
            const float4 s1 = *(const float4*)&D[(1*128 + m)*64 + 4*jl];
            const float4 s2 = *(const float4*)&D[(2*128 + m)*64 + 4*jl];
            const float4 s3 = *(const float4*)&D[(3*128 + m)*64 + 4*jl];
            const float gr = s0.x + s1.x + s2.x + s3.x;
            const float gz = s0.y + s1.y + s2.y + s3.y;
            const float gi = s0.z + s1.z + s2.z + s3.z;
            const float gh = s0.w + s1.w + s2.w + s3.w;

            const long mg = m0 + m;
            const long j  = (long)by * 16 + jl;

            const float rr = 1.f / (1.f + expf(-gr));
            const float zz = 1.f / (1.f + expf(-gz));
            const float nn = tanhf(fmaf(rr, gh, gi));
            const float o  = nn + zz * (hp[it] - nn);
            hp[it] = o;

            __builtin_nontemporal_store(o, &outk[mg * KH + j]);

            // hT writeback (hi only) — sc0 sc1 write-through
            const unsigned short hi = f2bf(o);
            const int kk  = (int)j;
            const int tc2 = kk >> 5;
            const int kg2 = (kk >> 4) & 1;
            const int lh  = (kk >> 3) & 1;
            const int e2  = kk & 7;
            const int mh2 = (m >> 6) & 1;
            const int mt2 = (m >> 5) & 1;
            const int row = m & 31;
            const long ub = (long)tc2*32768 + bx*8192 + mh2*2048 + mt2*1024
                          + kg2*512 + (lh*32 + row)*8 + e2;
            unsigned short* p0 = hTw + ub;
            asm volatile("global_store_short %0, %1, off sc0 sc1"
                         :: "v"(p0), "v"((unsigned)hi) : "memory");
        }
        asm volatile("s_waitcnt vmcnt(0)" ::: "memory");   // hT visible before barrier add
    }
}

// ---------------------------------------------------------------------------
extern "C" void kernel_launch(void* const* d_in, const int* in_sizes, int n_in,
                              void* d_out, int out_size, void* d_ws, size_t ws_size,
                              hipStream_t stream)
{
    const float* c   = (const float*)d_in[0];
    // d_in[1] = K (fixed 96)
    const float* wih = (const float*)d_in[2];
    const float* whh = (const float*)d_in[3];
    const float* bih = (const float*)d_in[4];
    const float* bhh = (const float*)d_in[5];
    float* out = (float*)d_out;

    unsigned short* blob0 = (unsigned short*)d_ws;            // 8.39M ushort
    unsigned short* blob1 = blob0 + 8388608L;
    float*          bcJ   = (float*)(blob1 + 8388608L);       // 4096 f32
    unsigned short* hTa   = (unsigned short*)(bcJ + 4096);    // 1M ushort
    unsigned short* hTb   = hTa + 1048576L;
    unsigned int*   bar   = (unsigned int*)(hTb + 1048576L);  // 512 u32

    prep_w  <<<dim3(32768, 2), 256, 0, stream>>>(wih, whh, blob0, blob1);
    prep_bcJ<<<dim3(16),       256, 0, stream>>>(bih, bhh, bcJ, bar);
    prep_h0 <<<dim3(2048),     256, 0, stream>>>(c, hTa);

    void* args[] = { (void*)&blob0, (void*)&blob1, (void*)&hTa, (void*)&hTb,
                     (void*)&c, (void*)&bcJ, (void*)&out, (void*)&bar };
    hipLaunchCooperativeKernel((const void*)gru_all, dim3(256), dim3(512),
                               args, 0, stream);
}

// Round 13
// 1274.263 us; speedup vs baseline: 1.4963x; 1.1774x over previous
//
#include <hip/hip_runtime.h>
#include <math.h>

#define H 1024
#define BATCH 512
#define KSTEPS 96
#define KH ((long)KSTEPS * H)

typedef __attribute__((ext_vector_type(8))) short short8;
typedef __attribute__((ext_vector_type(16))) float f32x16;

__device__ __forceinline__ unsigned short f2bf(float x) {
    union { float f; unsigned int u; } v; v.f = x;
    unsigned int r = v.u + 0x7fffu + ((v.u >> 16) & 1u);
    return (unsigned short)(r >> 16);
}
__device__ __forceinline__ float bf2f(unsigned short h) {
    union { unsigned int u; float f; } v; v.u = ((unsigned int)h) << 16;
    return v.f;
}

// async global->LDS 16B/lane; dst wave-uniform base (HW adds lane*16)
__device__ __forceinline__ void glds16(const void* g, void* l) {
    __builtin_amdgcn_global_load_lds(
        (const __attribute__((address_space(1))) void*)g,
        (__attribute__((address_space(3))) void*)l, 16, 0, 0);
}
#define MEMFENCE asm volatile("" ::: "memory")

// ---------------------------------------------------------------------------
// Workspace layouts (32x32x16 MFMA fragment order):
//  blob0/blob1: [32 tc][64 by][2 s][2 jt][2 kg][64 l][8 e] bf16   (W hi+lo)
//  bcJ: [4096] f32 J-interleaved fused biases
//  hTa/hTb: [32 tc][4 bx][2 s][2 mh][2 mt][2 kg][64 l][8 e] bf16 — ONLY s=0
//           (hi) used (2-product scheme).
//  bar: [512] u32 — [g*32] group counters, [256] global, [288] go-epoch
// ---------------------------------------------------------------------------

__global__ void prep_w(const float* __restrict__ wih,
                       const float* __restrict__ whh,
                       unsigned short* __restrict__ blob0,
                       unsigned short* __restrict__ blob1)
{
    const unsigned int f = blockIdx.x * 256 + threadIdx.x;  // 0..8388607
    const int e  = f & 7;
    const int l  = (f >> 3) & 63;
    const int kg = (f >> 9) & 1;
    const int jt = (f >> 10) & 1;
    const int s  = (f >> 11) & 1;
    const int by = (f >> 12) & 63;
    const int tc = (f >> 18) & 31;
    const int b  = blockIdx.y;      // blob select

    const int J = by * 64 + jt * 32 + (l & 31);
    const int g = J & 3;
    const long j = J >> 2;
    const long k = (long)tc * 32 + kg * 16 + (l >> 5) * 8 + e;

    float v = 0.f;
    if (b == 1) {
        if (g == 0)      v = wih[j*1024 + k]           + whh[j*1024 + k];
        else if (g == 1) v = wih[(1024+j)*1024 + k]    + whh[(1024+j)*1024 + k];
        else if (g == 2) v = wih[(2048+j)*1024 + k];
        else             v = whh[(2048+j)*1024 + k];
    } else {
        if (g == 0)      v = whh[j*1024 + k];
        else if (g == 1) v = whh[(1024+j)*1024 + k];
        else if (g == 2) v = 0.f;
        else             v = whh[(2048+j)*1024 + k];
    }
    const unsigned short hi = f2bf(v);
    unsigned short* blob = (b == 0) ? blob0 : blob1;
    blob[f] = (s == 0) ? hi : f2bf(v - bf2f(hi));
}

__global__ void prep_bcJ(const float* __restrict__ bih,
                         const float* __restrict__ bhh,
                         float* __restrict__ bcJ,
                         unsigned int* __restrict__ bar)
{
    const int J = blockIdx.x * 256 + threadIdx.x;   // 0..4095
    const int g = J & 3;
    const int j = J >> 2;
    float v;
    if (g == 0)      v = bih[j]        + bhh[j];
    else if (g == 1) v = bih[1024 + j] + bhh[1024 + j];
    else if (g == 2) v = bih[2048 + j];
    else             v = bhh[2048 + j];
    bcJ[J] = v;
    if (blockIdx.x == 0) {                 // zero barrier state (512 u32)
        bar[threadIdx.x]       = 0u;
        bar[256 + threadIdx.x] = 0u;
    }
}

// c [512][1024] fp32 -> hT fragment layout, hi (s=0) only
__global__ void prep_h0(const float* __restrict__ cin,
                        unsigned short* __restrict__ hT)
{
    const unsigned int f = blockIdx.x * 256 + threadIdx.x;   // 0..524287
    const int e  = f & 7;
    const int l  = (f >> 3) & 63;
    const int kg = (f >> 9) & 1;
    const int mt = (f >> 10) & 1;
    const int mh = (f >> 11) & 1;
    const int bx = (f >> 12) & 3;
    const int tc = (f >> 14) & 31;

    const long m = bx * 128 + mh * 64 + mt * 32 + (l & 31);
    const long k = (long)tc * 32 + kg * 16 + (l >> 5) * 8 + e;

    const long addr = (long)tc*32768 + bx*8192 /* s=0 */ + mh*2048 + mt*1024
                    + kg*512 + l*8 + e;
    hT[addr] = f2bf(cin[m * 1024 + k]);
}

// ---------------------------------------------------------------------------
// Persistent GRU: all 96 steps in ONE cooperative launch.
// Grid 256 (1/CU), 512 threads (8 waves). 2-PRODUCT split:
//   W·h ≈ (W_hi + W_lo)·h_hi. 16 MFMA/chunk/wave.
// Coherence scheme (NO cache invalidates):
//   - W staged via glds16, stays L2-resident across all 96 steps (warm hits).
//   - hT written with sc0 sc1 write-through stores (to coherence point) and
//     READ with sc0 sc1 system-scope loads (bypass stale per-XCD L2).
//   - out write-only nontemporal; h_prev exact in hp[] registers.
// Cross-step sync: two-level counter barrier (relaxed agent atomics).
// ---------------------------------------------------------------------------
__global__ __launch_bounds__(512) void gru_all(
    const unsigned short* __restrict__ blob0,
    const unsigned short* __restrict__ blob1,
    unsigned short* __restrict__ hTa,
    unsigned short* __restrict__ hTb,
    const float* __restrict__ cin,
    const float* __restrict__ bcJ,
    float* __restrict__ out,
    unsigned int* bar)
{
    __shared__ __attribute__((aligned(16))) char smem[131072]; // W: 4gk x 3 x 8KB; D reuse 128KB

    const int tid  = threadIdx.x;
    const int lane = tid & 63;
    const int wv   = tid >> 6;        // 0..7
    const int gk   = wv >> 1;         // K-quarter 0..3
    const int mh   = wv & 1;          // m-half within 128

    const int id   = blockIdx.x;
    const int grp  = id & 7;
    const int slot = id >> 3;
    const int by   = grp * 8 + (slot & 7);   // 0..63  (J tile)
    const int bx   = slot >> 3;              // 0..3   (m tile)
    const long m0  = (long)bx * 128;

    const float bb0 = bcJ[by*64 + (lane & 31)];
    const float bb1 = bcJ[by*64 + 32 + (lane & 31)];

    // h_prev carried in registers: same (m,j) per thread every step
    float hp[4];
    #pragma unroll
    for (int it = 0; it < 4; ++it) {
        const int qi = it * 512 + tid;
        const int jl = qi & 15;
        const int m  = qi >> 4;
        hp[it] = cin[(m0 + m) * 1024 + (long)by * 16 + jl];
    }

    #pragma unroll 1
    for (int k = 0; k < KSTEPS; ++k) {
        if (k > 0) {
            __syncthreads();           // epilogue stores drained (vmcnt(0) at tail)
            if (tid == 0) {
                unsigned v = __hip_atomic_fetch_add(&bar[grp*32], 1u,
                                 __ATOMIC_RELAXED, __HIP_MEMORY_SCOPE_AGENT);
                if (v == 32u*(unsigned)k - 1u) {
                    unsigned w = __hip_atomic_fetch_add(&bar[256], 1u,
                                     __ATOMIC_RELAXED, __HIP_MEMORY_SCOPE_AGENT);
                    if (w == 8u*(unsigned)k - 1u)
                        __hip_atomic_store(&bar[288], (unsigned)k,
                                           __ATOMIC_RELAXED, __HIP_MEMORY_SCOPE_AGENT);
                }
                while (__hip_atomic_load(&bar[288], __ATOMIC_RELAXED,
                                         __HIP_MEMORY_SCOPE_AGENT) < (unsigned)k)
                    __builtin_amdgcn_s_sleep(2);
            }
            __syncthreads();
        }

        const unsigned short* wbl = (k == 0) ? blob0 : blob1;
        const unsigned short* hTr = (k & 1) ? hTb : hTa;
        unsigned short*       hTw = (k & 1) ? hTa : hTb;
        float* outk = out + (long)k * H;

        const char* wsrc = (const char*)wbl + (long)by * 8192;   // + tc*524288
        const char* hsrc = (const char*)hTr + (long)bx * 16384;  // + tc*65536

        f32x16 acc[2][2];   // [mt][jt]
        {
            const float a0 = (gk == 0) ? bb0 : 0.f;
            const float a1 = (gk == 0) ? bb1 : 0.f;
            #pragma unroll
            for (int mt = 0; mt < 2; ++mt)
                #pragma unroll
                for (int r = 0; r < 16; ++r) { acc[mt][0][r] = a0; acc[mt][1][r] = a1; }
        }

        short8 Aev[4], Aod[4];   // [mt*2+kg], hi only

        // system-scope loads: bypass stale per-XCD L2, read coherence point
        auto loadA = [&](int c, short8* A) {
            const char* hs = hsrc + (long)(gk * 8 + c) * 65536;
            #pragma unroll
            for (int mt = 0; mt < 2; ++mt)
                #pragma unroll
                for (int kg = 0; kg < 2; ++kg) {
                    const void* p = hs + (long)(((mh*2+mt)*2)+kg)*1024 + lane*16;
                    asm volatile("global_load_dwordx4 %0, %1, off sc0 sc1"
                                 : "=v"(A[mt*2+kg]) : "v"(p) : "memory");
                }
        };
        auto stageW = [&](int c) {
            const char* ws = wsrc + (long)(gk * 8 + c) * 524288;
            char* dst = smem + gk * 24576 + (c % 3) * 8192;
            #pragma unroll
            for (int o = 0; o < 4; ++o)
                glds16(ws + (mh*4+o)*1024 + lane*16, dst + (mh*4+o)*1024);
        };
        auto compute = [&](const char* wb, const short8* A) {
            #pragma unroll
            for (int kg = 0; kg < 2; ++kg) {
                const short8 bh0 = *(const short8*)(wb + (0*4 + 0*2 + kg)*1024 + lane*16);
                const short8 bh1 = *(const short8*)(wb + (0*4 + 1*2 + kg)*1024 + lane*16);
                const short8 bl0 = *(const short8*)(wb + (1*4 + 0*2 + kg)*1024 + lane*16);
                const short8 bl1 = *(const short8*)(wb + (1*4 + 1*2 + kg)*1024 + lane*16);
                const short8 ah0 = A[0*2 + kg];
                const short8 ah1 = A[1*2 + kg];
                // p0: Ah*Bh (4 independent chains)
                acc[0][0] = __builtin_amdgcn_mfma_f32_32x32x16_bf16(ah0, bh0, acc[0][0], 0, 0, 0);
                acc[0][1] = __builtin_amdgcn_mfma_f32_32x32x16_bf16(ah0, bh1, acc[0][1], 0, 0, 0);
                acc[1][0] = __builtin_amdgcn_mfma_f32_32x32x16_bf16(ah1, bh0, acc[1][0], 0, 0, 0);
                acc[1][1] = __builtin_amdgcn_mfma_f32_32x32x16_bf16(ah1, bh1, acc[1][1], 0, 0, 0);
                // p1: Ah*Bl
                acc[0][0] = __builtin_amdgcn_mfma_f32_32x32x16_bf16(ah0, bl0, acc[0][0], 0, 0, 0);
                acc[0][1] = __builtin_amdgcn_mfma_f32_32x32x16_bf16(ah0, bl1, acc[0][1], 0, 0, 0);
                acc[1][0] = __builtin_amdgcn_mfma_f32_32x32x16_bf16(ah1, bl0, acc[1][0], 0, 0, 0);
                acc[1][1] = __builtin_amdgcn_mfma_f32_32x32x16_bf16(ah1, bl1, acc[1][1], 0, 0, 0);
            }
        };

        // ---- prologue: A(0), W(0), W(1) — 12 vmem ops; vmcnt(4) leaves W1 ----
        loadA(0, Aev); MEMFENCE;
        stageW(0); MEMFENCE;
        stageW(1); MEMFENCE;
        asm volatile("s_waitcnt vmcnt(4)" ::: "memory");
        __builtin_amdgcn_sched_barrier(0);
        __builtin_amdgcn_s_barrier();

        #define CHUNK(c, Acur, Anext)                                          \
        {                                                                      \
            if ((c) < 7) { loadA((c)+1, Anext); MEMFENCE; }                    \
            if ((c) < 6) { stageW((c)+2); MEMFENCE; }                          \
            __builtin_amdgcn_sched_barrier(0);                                 \
            __builtin_amdgcn_s_setprio(1);                                     \
            compute(smem + gk*24576 + ((c)%3)*8192, Acur);                     \
            __builtin_amdgcn_s_setprio(0);                                     \
            if ((c) <= 5)      asm volatile("s_waitcnt vmcnt(4)" ::: "memory");\
            else if ((c) == 6) asm volatile("s_waitcnt vmcnt(0)" ::: "memory");\
            __builtin_amdgcn_sched_barrier(0);                                 \
            __builtin_amdgcn_s_barrier();                                      \
        }
        CHUNK(0, Aev, Aod) CHUNK(1, Aod, Aev) CHUNK(2, Aev, Aod) CHUNK(3, Aod, Aev)
        CHUNK(4, Aev, Aod) CHUNK(5, Aod, Aev) CHUNK(6, Aev, Aod) CHUNK(7, Aod, Aev)
        #undef CHUNK

        __syncthreads();   // LDS reads done; smem becomes epilogue scratch

        // ---- epilogue: dump partials, 4-way reduce, gates ----
        float* D = (float*)smem;   // [4 gk][128 m][64 J]
        #pragma unroll
        for (int mt = 0; mt < 2; ++mt)
            #pragma unroll
            for (int jt = 0; jt < 2; ++jt)
                #pragma unroll
                for (int r = 0; r < 16; ++r) {
                    const int r32 = (r & 3) + 8 * (r >> 2) + 4 * (lane >> 5);
                    const int m  = mh * 64 + mt * 32 + r32;
                    const int J  = jt * 32 + (lane & 31);
                    D[(gk * 128 + m) * 64 + J] = acc[mt][jt][r];
                }
        __syncthreads();

        #pragma unroll
        for (int it = 0; it < 4; ++it) {
            const int qi = it * 512 + tid;     // 0..2047
            const int jl = qi & 15;
            const int m  = qi >> 4;            // 0..127
            const float4 s0 = *(const float4*)&D[(0*128 + m)*64 + 4*jl];
            const float4 s1 = *(const float4*)&D[(1*128 + m)*64 + 4*jl];
            const float4 s2 = *(const float4*)&D[(2*128 + m)*64 + 4*jl];
            const float4 s3 = *(const float4*)&D[(3*128 + m)*64 + 4*jl];
            const float gr = s0.x + s1.x + s2.x + s3.x;
            const float gz = s0.y + s1.y + s2.y + s3.y;
            const float gi = s0.z + s1.z + s2.z + s3.z;
            const float gh = s0.w + s1.w + s2.w + s3.w;

            const long mg = m0 + m;
            const long j  = (long)by * 16 + jl;

            const float rr = 1.f / (1.f + expf(-gr));
            const float zz = 1.f / (1.f + expf(-gz));
            const float nn = tanhf(fmaf(rr, gh, gi));
            const float o  = nn + zz * (hp[it] - nn);
            hp[it] = o;

            __builtin_nontemporal_store(o, &outk[mg * KH + j]);

            // hT writeback (hi only) — sc0 sc1 write-through
            const unsigned short hi = f2bf(o);
            const int kk  = (int)j;
            const int tc2 = kk >> 5;
            const int kg2 = (kk >> 4) & 1;
            const int lh  = (kk >> 3) & 1;
            const int e2  = kk & 7;
            const int mh2 = (m >> 6) & 1;
            const int mt2 = (m >> 5) & 1;
            const int row = m & 31;
            const long ub = (long)tc2*32768 + bx*8192 + mh2*2048 + mt2*1024
                          + kg2*512 + (lh*32 + row)*8 + e2;
            unsigned short* p0 = hTw + ub;
            asm volatile("global_store_short %0, %1, off sc0 sc1"
                         :: "v"(p0), "v"((unsigned)hi) : "memory");
        }
        asm volatile("s_waitcnt vmcnt(0)" ::: "memory");   // hT visible before barrier add
    }
}

// ---------------------------------------------------------------------------
extern "C" void kernel_launch(void* const* d_in, const int* in_sizes, int n_in,
                              void* d_out, int out_size, void* d_ws, size_t ws_size,
                              hipStream_t stream)
{
    const float* c   = (const float*)d_in[0];
    // d_in[1] = K (fixed 96)
    const float* wih = (const float*)d_in[2];
    const float* whh = (const float*)d_in[3];
    const float* bih = (const float*)d_in[4];
    const float* bhh = (const float*)d_in[5];
    float* out = (float*)d_out;

    unsigned short* blob0 = (unsigned short*)d_ws;            // 8.39M ushort
    unsigned short* blob1 = blob0 + 8388608L;
    float*          bcJ   = (float*)(blob1 + 8388608L);       // 4096 f32
    unsigned short* hTa   = (unsigned short*)(bcJ + 4096);    // 1M ushort
    unsigned short* hTb   = hTa + 1048576L;
    unsigned int*   bar   = (unsigned int*)(hTb + 1048576L);  // 512 u32

    prep_w  <<<dim3(32768, 2), 256, 0, stream>>>(wih, whh, blob0, blob1);
    prep_bcJ<<<dim3(16),       256, 0, stream>>>(bih, bhh, bcJ, bar);
    prep_h0 <<<dim3(2048),     256, 0, stream>>>(c, hTa);

    void* args[] = { (void*)&blob0, (void*)&blob1, (void*)&hTa, (void*)&hTb,
                     (void*)&c, (void*)&bcJ, (void*)&out, (void*)&bar };
    hipLaunchCooperativeKernel((const void*)gru_all, dim3(256), dim3(512),
                               args, 0, stream);
}